// Round 3
// baseline (467.745 us; speedup 1.0000x reference)
//
#include <hip/hip_runtime.h>
#include <hip/hip_bf16.h>

typedef __hip_bfloat16 bf16;
typedef __attribute__((ext_vector_type(8))) short short8;
typedef __attribute__((ext_vector_type(4))) float floatx4;

#define B_DIM 8192
#define H_DIM 1024
#define N_DIM 4096   // 4 gates * H
#define K_HALF 1024

#define BM 128
#define BN 128
#define BK 32

union BS { bf16 b; short s; };

__device__ __forceinline__ short cvt1(float f) {
  BS u; u.b = __float2bfloat16(f); return u.s;
}

// load 8 consecutive floats, convert to 8 bf16 (packed short8)
__device__ __forceinline__ short8 ld_cvt8(const float* p) {
  const float4 lo = *(const float4*)p;
  const float4 hi = *(const float4*)(p + 4);
  short8 r;
  r[0] = cvt1(lo.x); r[1] = cvt1(lo.y); r[2] = cvt1(lo.z); r[3] = cvt1(lo.w);
  r[4] = cvt1(hi.x); r[5] = cvt1(hi.y); r[6] = cvt1(hi.z); r[7] = cvt1(hi.w);
  return r;
}

// One fused GEMM over K=2048: k<1024 uses (x, W), k>=1024 uses (h, U).
// W[g][hh][i] is flat W[n*1024+i] with n=g*1024+hh -> already B^T layout.
// fp32 inputs, converted to bf16 during staging. Writes pre-activation
// gates[m][n] (bf16) to workspace.
__global__ __launch_bounds__(256) void gemm_gates(
    const float* __restrict__ x, const float* __restrict__ h,
    const float* __restrict__ W, const float* __restrict__ U,
    bf16* __restrict__ gates) {
  __shared__ __align__(16) bf16 sA[BM * BK];  // 8 KB, row-major [r][kk]
  __shared__ __align__(16) bf16 sB[BN * BK];  // 8 KB

  const int tid  = threadIdx.x;
  const int lane = tid & 63;
  const int wv   = tid >> 6;

  const int nt = blockIdx.x & 31;   // N_DIM/BN = 32
  const int mt = blockIdx.x >> 5;   // B_DIM/BM = 64
  const long m0 = (long)mt * BM;
  const long n0 = (long)nt * BN;

  // staging map: thread -> (row sr, k-col skk); 256 threads cover 64 rows x 32k
  const int sr  = (wv << 4) + (lane >> 2);   // 0..63
  const int skk = (lane & 3) << 3;           // 0,8,16,24
  const long aOff = (m0 + sr) * (long)K_HALF + skk;
  const long bOff = (n0 + sr) * (long)K_HALF + skk;

  // compute phase: wave (wm,wn) quadrant, 4x4 grid of 16x16x32 MFMAs
  const int wm = ((wv >> 1) & 1) << 6;
  const int wn = (wv & 1) << 6;
  const int fr = lane & 15;          // A: m index / B: n index
  const int fk = (lane >> 4) << 3;   // k chunk (quad*8)

  floatx4 acc[4][4];
#pragma unroll
  for (int i = 0; i < 4; ++i)
#pragma unroll
    for (int j = 0; j < 4; ++j) acc[i][j] = (floatx4){0.f, 0.f, 0.f, 0.f};

  for (int kt = 0; kt < 64; ++kt) {
    const bool firstHalf = (kt < 32);
    const float* Abase = firstHalf ? x : h;
    const float* Bbase = firstHalf ? W : U;
    const long koff = (long)(kt * BK) - (firstHalf ? 0 : 1024);

    // fp32 loads + convert-to-bf16 in registers
    const short8 a0 = ld_cvt8(Abase + aOff + koff);
    const short8 a1 = ld_cvt8(Abase + aOff + 64 * (long)K_HALF + koff);
    const short8 b0 = ld_cvt8(Bbase + bOff + koff);
    const short8 b1 = ld_cvt8(Bbase + bOff + 64 * (long)K_HALF + koff);

    __syncthreads();  // all waves done reading previous tile
    *(short8*)&sA[sr * BK + skk]        = a0;
    *(short8*)&sA[(sr + 64) * BK + skk] = a1;
    *(short8*)&sB[sr * BK + skk]        = b0;
    *(short8*)&sB[(sr + 64) * BK + skk] = b1;
    __syncthreads();  // staging visible to all waves

    short8 af[4], bfr[4];
#pragma unroll
    for (int i = 0; i < 4; ++i) {
      af[i]  = *(const short8*)&sA[(wm + i * 16 + fr) * BK + fk];
      bfr[i] = *(const short8*)&sB[(wn + i * 16 + fr) * BK + fk];
    }
#pragma unroll
    for (int i = 0; i < 4; ++i)
#pragma unroll
      for (int j = 0; j < 4; ++j)
        acc[i][j] = __builtin_amdgcn_mfma_f32_16x16x32_bf16(af[i], bfr[j],
                                                            acc[i][j], 0, 0, 0);
  }

  // C/D layout: col = lane&15, row = (lane>>4)*4 + reg
  const int rquad = (lane >> 4) << 2;
#pragma unroll
  for (int i = 0; i < 4; ++i) {
#pragma unroll
    for (int j = 0; j < 4; ++j) {
      const long mb = m0 + wm + i * 16 + rquad;
      const long nn = n0 + wn + j * 16 + fr;
#pragma unroll
      for (int r = 0; r < 4; ++r) {
        gates[(mb + r) * (long)N_DIM + nn] = __float2bfloat16(acc[i][j][r]);
      }
    }
  }
}

__device__ __forceinline__ float sigmoidf_(float v) {
  return 1.0f / (1.0f + __expf(-v));
}
__device__ __forceinline__ float tanhf_(float v) {
  return 1.0f - 2.0f / (__expf(2.0f * v) + 1.0f);  // safe at +/-inf
}

union V8 {
  uint4 u;
  bf16 e[8];
};

struct F8 { float4 lo, hi; };
__device__ __forceinline__ F8 ldf8(const float* p) {
  F8 r; r.lo = *(const float4*)p; r.hi = *(const float4*)(p + 4); return r;
}
__device__ __forceinline__ float f8get(const F8& v, int k) {
  return k < 4 ? (k == 0 ? v.lo.x : k == 1 ? v.lo.y : k == 2 ? v.lo.z : v.lo.w)
               : (k == 4 ? v.hi.x : k == 5 ? v.hi.y : k == 6 ? v.hi.z : v.hi.w);
}

// elementwise: bias + activations + cell update; 8 elems/thread
// gates bf16, everything else fp32
__global__ __launch_bounds__(256) void lstm_epilogue(
    const bf16* __restrict__ gates, const float* __restrict__ c,
    const float* __restrict__ bW, const float* __restrict__ bU,
    float* __restrict__ out) {
  const long idx = (long)blockIdx.x * 256 + threadIdx.x;  // 0 .. 1M-1
  const long b  = idx >> 7;        // batch row
  const int hh  = (int)(idx & 127) << 3;

  const long gbase = b * (long)N_DIM + hh;
  V8 vi, vf, vo, vg;
  vi.u = *(const uint4*)(gates + gbase);
  vf.u = *(const uint4*)(gates + gbase + 1024);
  vo.u = *(const uint4*)(gates + gbase + 2048);
  vg.u = *(const uint4*)(gates + gbase + 3072);
  const F8 vc = ldf8(c + b * (long)H_DIM + hh);
  const F8 bi = ldf8(bW + hh);
  const F8 bf_ = ldf8(bW + 1024 + hh);
  const F8 bo = ldf8(bW + 2048 + hh);
  const F8 bg = ldf8(bW + 3072 + hh);
  const F8 ui = ldf8(bU + hh);
  const F8 uf = ldf8(bU + 1024 + hh);
  const F8 uo = ldf8(bU + 2048 + hh);
  const F8 ug = ldf8(bU + 3072 + hh);

  float hn[8], cn[8];
#pragma unroll
  for (int k = 0; k < 8; ++k) {
    float gi = __bfloat162float(vi.e[k]) + f8get(bi, k) + f8get(ui, k);
    float gf = __bfloat162float(vf.e[k]) + f8get(bf_, k) + f8get(uf, k);
    float go = __bfloat162float(vo.e[k]) + f8get(bo, k) + f8get(uo, k);
    float gg = __bfloat162float(vg.e[k]) + f8get(bg, k) + f8get(ug, k);
    float I = sigmoidf_(gi);
    float F = sigmoidf_(gf);
    float O = sigmoidf_(go);
    float G = tanhf_(gg);
    float cv = F * f8get(vc, k) + I * G;
    float hv = O * tanhf_(cv);
    hn[k] = hv;
    cn[k] = cv;
  }

  const long obase = b * (long)H_DIM + hh;
  const long BH = (long)B_DIM * H_DIM;  // 8388608
  float4 h_lo = {hn[0], hn[1], hn[2], hn[3]};
  float4 h_hi = {hn[4], hn[5], hn[6], hn[7]};
  float4 c_lo = {cn[0], cn[1], cn[2], cn[3]};
  float4 c_hi = {cn[4], cn[5], cn[6], cn[7]};
  *(float4*)(out + obase)          = h_lo;  // output 0: h_new
  *(float4*)(out + obase + 4)      = h_hi;
  *(float4*)(out + BH + obase)     = h_lo;  // output 1: h_new (tuple dup)
  *(float4*)(out + BH + obase + 4) = h_hi;
  *(float4*)(out + 2 * BH + obase)     = c_lo;  // output 2: c_new
  *(float4*)(out + 2 * BH + obase + 4) = c_hi;
}

extern "C" void kernel_launch(void* const* d_in, const int* in_sizes, int n_in,
                              void* d_out, int out_size, void* d_ws, size_t ws_size,
                              hipStream_t stream) {
  const float* x  = (const float*)d_in[0];
  const float* h  = (const float*)d_in[1];
  const float* c  = (const float*)d_in[2];
  const float* W  = (const float*)d_in[3];
  const float* bW = (const float*)d_in[4];
  const float* U  = (const float*)d_in[5];
  const float* bU = (const float*)d_in[6];
  float* out  = (float*)d_out;
  bf16* gates = (bf16*)d_ws;  // needs 4*B*H*2 = 64 MB of workspace

  // GEMM: M=8192, N=4096, K=2048 -> (64 m-tiles) x (32 n-tiles) = 2048 blocks
  gemm_gates<<<2048, 256, 0, stream>>>(x, h, W, U, gates);
  // epilogue: 1M threads, 8 elems each
  lstm_epilogue<<<4096, 256, 0, stream>>>(gates, c, bW, bU, out);
}

// Round 4
// 411.142 us; speedup vs baseline: 1.1377x; 1.1377x over previous
//
#include <hip/hip_runtime.h>
#include <hip/hip_bf16.h>

typedef __hip_bfloat16 bf16;
typedef __attribute__((ext_vector_type(8))) short short8;
typedef __attribute__((ext_vector_type(4))) float floatx4;

#define B_DIM 8192
#define H_DIM 1024
#define KSUM 2048      // fused K: 1024 (x·W) + 1024 (h·U)
#define BM 128
#define BN 128
#define BK 32
#define CEX_STRIDE 68  // padded floats/row in C-exchange LDS (breaks conflicts)

union BS { bf16 b; short s; };
__device__ __forceinline__ short cvt1(float f) {
  BS u; u.b = __float2bfloat16(f); return u.s;
}
__device__ __forceinline__ short8 cvt8(float4 lo, float4 hi) {
  short8 r;
  r[0] = cvt1(lo.x); r[1] = cvt1(lo.y); r[2] = cvt1(lo.z); r[3] = cvt1(lo.w);
  r[4] = cvt1(hi.x); r[5] = cvt1(hi.y); r[6] = cvt1(hi.z); r[7] = cvt1(hi.w);
  return r;
}

// async global->LDS, 16B/lane; lds dest is wave-uniform base + lane*16
__device__ __forceinline__ void async_ld16(const bf16* g, bf16* lds) {
  __builtin_amdgcn_global_load_lds(
      (const __attribute__((address_space(1))) unsigned int*)g,
      (__attribute__((address_space(3))) unsigned int*)lds,
      16, 0, 0);
}

// Ac[row][k] bf16: k<1024 -> x[row][k], else h[row][k-1024]
__global__ __launch_bounds__(256) void cvt_pack_A(
    const float* __restrict__ x, const float* __restrict__ h,
    bf16* __restrict__ Ac) {
  const int idx = blockIdx.x * 256 + threadIdx.x;   // 2M threads
  const long row = idx >> 8;
  const int k0 = (idx & 255) << 3;                  // 0..2040, never straddles
  const float* src = (k0 < 1024) ? (x + row * 1024 + k0)
                                 : (h + row * 1024 + (k0 - 1024));
  const float4 lo = *(const float4*)src;
  const float4 hi = *(const float4*)(src + 4);
  *(short8*)(Ac + row * KSUM + k0) = cvt8(lo, hi);
}

// Bc[r][k] bf16, gate-interleaved rows: r = hh*4+g;
// k<1024 -> W[g][hh][k], else U[g][hh][k-1024]
__global__ __launch_bounds__(256) void cvt_pack_B(
    const float* __restrict__ W, const float* __restrict__ U,
    bf16* __restrict__ Bc) {
  const int idx = blockIdx.x * 256 + threadIdx.x;   // 1M threads
  const long r = idx >> 8;
  const int k0 = (idx & 255) << 3;
  const int g = (int)(r & 3);
  const long hh = r >> 2;
  const long base = (long)g * (H_DIM * H_DIM) + hh * H_DIM;
  const float* src = (k0 < 1024) ? (W + base + k0) : (U + base + (k0 - 1024));
  const float4 lo = *(const float4*)src;
  const float4 hi = *(const float4*)(src + 4);
  *(short8*)(Bc + r * KSUM + k0) = cvt8(lo, hi);
}

__device__ __forceinline__ float sigmoidf_(float v) {
  return 1.0f / (1.0f + __expf(-v));
}
__device__ __forceinline__ float tanhf_(float v) {
  return 1.0f - 2.0f / (__expf(2.0f * v) + 1.0f);  // safe at +/-inf
}
__device__ __forceinline__ float getc(const float4& v, int t) {
  return t == 0 ? v.x : t == 1 ? v.y : t == 2 ? v.z : v.w;
}

// GEMM M=8192,N=4096,K=2048 (bf16 MFMA) + fused LSTM epilogue.
// Output col n: gate g = n&3, h-col = n>>2 (Bc rows are gate-interleaved).
__global__ __launch_bounds__(256) void gemm_lstm(
    const bf16* __restrict__ Ac, const bf16* __restrict__ Bc,
    const float* __restrict__ cprev_g, const float* __restrict__ bW,
    const float* __restrict__ bU, float* __restrict__ out) {
  __shared__ __align__(16) char smem[4 * 16 * CEX_STRIDE * 4];  // 17408 B
  bf16* sA = (bf16*)smem;             // 8 KB, [128][32] row-major
  bf16* sB = (bf16*)(smem + 8192);    // 8 KB
  float* cex = (float*)smem;          // epilogue exchange (per-wave 16x68)

  const int tid  = threadIdx.x;
  const int lane = tid & 63;
  const int wv   = tid >> 6;

  const int nt = blockIdx.x & 31;     // 4096/128 = 32 n-tiles
  const int mt = blockIdx.x >> 5;     // 8192/128 = 64 m-tiles
  const long m0 = (long)mt * BM;
  const long n0 = (long)nt * BN;

  // staging map: lane -> (row sr, k-col skk); LDS dest = waveBase + lane*16B
  const int sr  = (wv << 4) + (lane >> 2);   // 0..63
  const int skk = (lane & 3) << 3;           // 0,8,16,24
  const bf16* aG = Ac + (m0 + sr) * (long)KSUM + skk;
  const bf16* bG = Bc + (n0 + sr) * (long)KSUM + skk;
  bf16* sA0 = sA + (wv << 9);         // wv*512 elems = wv*1024 B
  bf16* sA1 = sA + (wv << 9) + 2048;  // rows +64
  bf16* sB0 = sB + (wv << 9);
  bf16* sB1 = sB + (wv << 9) + 2048;

  // compute phase: 2x2 wave grid, 4x4 MFMA frags each
  const int wm = ((wv >> 1) & 1) << 6;
  const int wn = (wv & 1) << 6;
  const int col16 = lane & 15;
  const int fk = (lane >> 4) << 3;

  floatx4 acc[4][4];
#pragma unroll
  for (int i = 0; i < 4; ++i)
#pragma unroll
    for (int j = 0; j < 4; ++j) acc[i][j] = (floatx4){0.f, 0.f, 0.f, 0.f};

  for (int kt = 0; kt < 64; ++kt) {
    const long koff = (long)kt * BK;
    __syncthreads();  // prior tile's frag reads done before overwrite
    async_ld16(aG + koff, sA0);
    async_ld16(aG + 64 * (long)KSUM + koff, sA1);
    async_ld16(bG + koff, sB0);
    async_ld16(bG + 64 * (long)KSUM + koff, sB1);
    __syncthreads();  // drains vmcnt -> staged tile visible

    short8 af[4], bfr[4];
#pragma unroll
    for (int i = 0; i < 4; ++i) {
      af[i]  = *(const short8*)&sA[(wm + i * 16 + col16) * BK + fk];
      bfr[i] = *(const short8*)&sB[(wn + i * 16 + col16) * BK + fk];
    }
#pragma unroll
    for (int i = 0; i < 4; ++i)
#pragma unroll
      for (int j = 0; j < 4; ++j)
        acc[i][j] = __builtin_amdgcn_mfma_f32_16x16x32_bf16(af[i], bfr[j],
                                                            acc[i][j], 0, 0, 0);
  }

  __syncthreads();  // repurpose LDS for C-exchange

  // ---- fused epilogue ----
  // C/D layout: col = lane&15, row = (lane>>4)*4 + reg
  const int rquad = (lane >> 4) << 2;
  const int row16 = lane & 15;        // reader role: local output row
  const int tq    = lane >> 4;        // reader role: h-subgroup 0..3
  // global h for this lane's 4 outputs: hglob..hglob+3
  const long hglob = (n0 >> 2) + (wn >> 2) + tq * 4;

  // bias sums, per gate, float4 over t (biases are tiny, L1-resident)
  float4 bsum[4];
#pragma unroll
  for (int g = 0; g < 4; ++g) {
    const float4 a = *(const float4*)(bW + g * H_DIM + hglob);
    const float4 b = *(const float4*)(bU + g * H_DIM + hglob);
    bsum[g] = (float4){a.x + b.x, a.y + b.y, a.z + b.z, a.w + b.w};
  }

  float* wx = cex + wv * (16 * CEX_STRIDE);   // wave-private region
  const long BH = (long)B_DIM * H_DIM;

  for (int ig = 0; ig < 4; ++ig) {
    // stage this 16-row group's 64 cols into LDS [row16][col64]
#pragma unroll
    for (int j = 0; j < 4; ++j)
#pragma unroll
      for (int r = 0; r < 4; ++r)
        wx[(rquad + r) * CEX_STRIDE + j * 16 + col16] = acc[ig][j][r];
    // within-wave LDS RAW: compiler orders via lgkmcnt (conservative alias)

    // gather 4 gates per output as float4: col64 = h16*4 + g
    float4 g4[4];
#pragma unroll
    for (int t = 0; t < 4; ++t)
      g4[t] = *(const float4*)&wx[row16 * CEX_STRIDE + (tq * 4 + t) * 4];

    const long mrow = m0 + wm + ig * 16 + row16;
    const float4 cp = *(const float4*)(cprev_g + mrow * H_DIM + hglob);

    float hn[4], cn[4];
#pragma unroll
    for (int t = 0; t < 4; ++t) {
      const float gi = g4[t].x + getc(bsum[0], t);
      const float gf = g4[t].y + getc(bsum[1], t);
      const float go = g4[t].z + getc(bsum[2], t);
      const float gg = g4[t].w + getc(bsum[3], t);
      const float I = sigmoidf_(gi);
      const float F = sigmoidf_(gf);
      const float O = sigmoidf_(go);
      const float G = tanhf_(gg);
      const float cv = F * getc(cp, t) + I * G;
      hn[t] = O * tanhf_(cv);
      cn[t] = cv;
    }
    const float4 hn4 = {hn[0], hn[1], hn[2], hn[3]};
    const float4 cn4 = {cn[0], cn[1], cn[2], cn[3]};
    const long ob = mrow * H_DIM + hglob;
    *(float4*)(out + ob)          = hn4;  // output 0: h_new
    *(float4*)(out + BH + ob)     = hn4;  // output 1: h_new (tuple dup)
    *(float4*)(out + 2 * BH + ob) = cn4;  // output 2: c_new
  }
}

extern "C" void kernel_launch(void* const* d_in, const int* in_sizes, int n_in,
                              void* d_out, int out_size, void* d_ws, size_t ws_size,
                              hipStream_t stream) {
  const float* x  = (const float*)d_in[0];
  const float* h  = (const float*)d_in[1];
  const float* c  = (const float*)d_in[2];
  const float* W  = (const float*)d_in[3];
  const float* bW = (const float*)d_in[4];
  const float* U  = (const float*)d_in[5];
  const float* bU = (const float*)d_in[6];
  float* out = (float*)d_out;

  bf16* Ac = (bf16*)d_ws;                               // 32 MB
  bf16* Bc = (bf16*)((char*)d_ws + (size_t)33554432);   // 16 MB

  cvt_pack_A<<<8192, 256, 0, stream>>>(x, h, Ac);
  cvt_pack_B<<<4096, 256, 0, stream>>>(W, U, Bc);
  // 64 m-tiles x 32 n-tiles
  gemm_lstm<<<2048, 256, 0, stream>>>(Ac, Bc, c, bW, bU, out);
}

// Round 5
// 394.210 us; speedup vs baseline: 1.1865x; 1.0430x over previous
//
#include <hip/hip_runtime.h>
#include <hip/hip_bf16.h>

typedef __hip_bfloat16 bf16;
typedef __attribute__((ext_vector_type(8))) short short8;
typedef __attribute__((ext_vector_type(4))) float floatx4;

#define B_DIM 8192
#define H_DIM 1024
#define KSUM 2048      // fused K: 1024 (x·W) + 1024 (h·U)
#define BM 128
#define BN 128
#define BK 64
#define KITER 32       // 2048 / 64
#define CEX_STRIDE 68  // padded floats/row in C-exchange LDS

union BS { bf16 b; short s; };
__device__ __forceinline__ short cvt1(float f) {
  BS u; u.b = __float2bfloat16(f); return u.s;
}
__device__ __forceinline__ short8 cvt8(float4 lo, float4 hi) {
  short8 r;
  r[0] = cvt1(lo.x); r[1] = cvt1(lo.y); r[2] = cvt1(lo.z); r[3] = cvt1(lo.w);
  r[4] = cvt1(hi.x); r[5] = cvt1(hi.y); r[6] = cvt1(hi.z); r[7] = cvt1(hi.w);
  return r;
}

// async global->LDS, 16B/lane; lds dest is wave-uniform base + lane*16
__device__ __forceinline__ void async_ld16(const bf16* g, bf16* lds) {
  __builtin_amdgcn_global_load_lds(
      (const __attribute__((address_space(1))) unsigned int*)g,
      (__attribute__((address_space(3))) unsigned int*)lds,
      16, 0, 0);
}

// Ac[row][k] bf16: k<1024 -> x[row][k], else h[row][k-1024]
__global__ __launch_bounds__(256) void cvt_pack_A(
    const float* __restrict__ x, const float* __restrict__ h,
    bf16* __restrict__ Ac) {
  const int idx = blockIdx.x * 256 + threadIdx.x;   // 2M threads
  const long row = idx >> 8;
  const int k0 = (idx & 255) << 3;
  const float* src = (k0 < 1024) ? (x + row * 1024 + k0)
                                 : (h + row * 1024 + (k0 - 1024));
  const float4 lo = *(const float4*)src;
  const float4 hi = *(const float4*)(src + 4);
  *(short8*)(Ac + row * KSUM + k0) = cvt8(lo, hi);
}

// Bc[r][k] bf16, gate-interleaved rows: r = hh*4+g;
// k<1024 -> W[g][hh][k], else U[g][hh][k-1024]
__global__ __launch_bounds__(256) void cvt_pack_B(
    const float* __restrict__ W, const float* __restrict__ U,
    bf16* __restrict__ Bc) {
  const int idx = blockIdx.x * 256 + threadIdx.x;   // 1M threads
  const long r = idx >> 8;
  const int k0 = (idx & 255) << 3;
  const int g = (int)(r & 3);
  const long hh = r >> 2;
  const long base = (long)g * (H_DIM * H_DIM) + hh * H_DIM;
  const float* src = (k0 < 1024) ? (W + base + k0) : (U + base + (k0 - 1024));
  const float4 lo = *(const float4*)src;
  const float4 hi = *(const float4*)(src + 4);
  *(short8*)(Bc + r * KSUM + k0) = cvt8(lo, hi);
}

__device__ __forceinline__ float sigmoidf_(float v) {
  return 1.0f / (1.0f + __expf(-v));
}
__device__ __forceinline__ float tanhf_(float v) {
  return 1.0f - 2.0f / (__expf(2.0f * v) + 1.0f);  // safe at +/-inf
}
__device__ __forceinline__ float getc(const float4& v, int t) {
  return t == 0 ? v.x : t == 1 ? v.y : t == 2 ? v.z : v.w;
}

// GEMM M=8192,N=4096,K=2048 (bf16 MFMA) + fused LSTM epilogue.
// LDS tiles are [row][chunk^(row&7)] XOR-swizzled (chunk = 8 bf16 = 16 B) to
// break frag-read bank aliasing while keeping the async dest contiguous.
__global__ __launch_bounds__(256) void gemm_lstm(
    const bf16* __restrict__ Ac, const bf16* __restrict__ Bc,
    const float* __restrict__ cprev_g, const float* __restrict__ bW,
    const float* __restrict__ bU, float* __restrict__ out) {
  __shared__ __align__(16) char smem[32768];
  bf16* sA = (bf16*)smem;             // 16 KB, [128][64] swizzled
  bf16* sB = (bf16*)(smem + 16384);   // 16 KB
  float* cex = (float*)smem;          // epilogue exchange (per-wave 16x68)

  const int tid  = threadIdx.x;
  const int lane = tid & 63;
  const int wv   = tid >> 6;

  // XCD-aware swizzle: xcd = blk&7; each XCD sweeps all 64 m-tiles against
  // one n-stripe (Bc stripe stays L2-resident), 4 stripes per XCD total.
  const int blk  = blockIdx.x;
  const int xcd  = blk & 7;
  const int slot = blk >> 3;          // 0..255 per xcd
  const int mt   = slot & 63;
  const int nt   = (xcd << 2) | (slot >> 6);
  const long m0 = (long)mt * BM;
  const long n0 = (long)nt * BN;

  // staging: call q covers rows [q*32+wv*8, +8); lane -> (row lrow, chunk)
  const int lrow   = lane >> 3;           // 0..7 row within 8-row group
  const int lchunk = lane & 7;            // dest chunk position
  const int schunk = lchunk ^ lrow;       // source chunk (row&7 == lrow)
  const bf16* aSrc = Ac + (m0 + wv * 8 + lrow) * (long)KSUM + schunk * 8;
  const bf16* bSrc = Bc + (n0 + wv * 8 + lrow) * (long)KSUM + schunk * 8;
  bf16* sAw = sA + (wv * 8) * 64;         // wave-uniform LDS bases
  bf16* sBw = sB + (wv * 8) * 64;

  // compute phase: 2x2 wave grid, 4x4 MFMA frags each
  const int wm = ((wv >> 1) & 1) << 6;
  const int wn = (wv & 1) << 6;
  const int col16 = lane & 15;
  const int quad  = lane >> 4;
  const int x7    = col16 & 7;

  floatx4 acc[4][4];
#pragma unroll
  for (int i = 0; i < 4; ++i)
#pragma unroll
    for (int j = 0; j < 4; ++j) acc[i][j] = (floatx4){0.f, 0.f, 0.f, 0.f};

  for (int kt = 0; kt < KITER; ++kt) {
    const long koff = (long)kt * BK;
    __syncthreads();  // prior tile's frag reads done before overwrite
#pragma unroll
    for (int q = 0; q < 4; ++q) {
      async_ld16(aSrc + koff + (long)q * (32 * (long)KSUM), sAw + q * (32 * 64));
      async_ld16(bSrc + koff + (long)q * (32 * (long)KSUM), sBw + q * (32 * 64));
    }
    __syncthreads();  // drains vmcnt -> staged tile visible

#pragma unroll
    for (int s = 0; s < 2; ++s) {
      const int cp = ((((s << 2) + quad) ^ x7) << 3);
      short8 af[4], bfr[4];
#pragma unroll
      for (int i = 0; i < 4; ++i) {
        af[i]  = *(const short8*)&sA[(wm + i * 16 + col16) * 64 + cp];
        bfr[i] = *(const short8*)&sB[(wn + i * 16 + col16) * 64 + cp];
      }
#pragma unroll
      for (int i = 0; i < 4; ++i)
#pragma unroll
        for (int j = 0; j < 4; ++j)
          acc[i][j] = __builtin_amdgcn_mfma_f32_16x16x32_bf16(af[i], bfr[j],
                                                              acc[i][j], 0, 0, 0);
    }
  }

  __syncthreads();  // repurpose LDS for C-exchange

  // ---- fused epilogue ----
  // C/D layout: col = lane&15, row = (lane>>4)*4 + reg
  const int rquad = (lane >> 4) << 2;
  const int row16 = lane & 15;        // reader role: local output row
  const int tq    = lane >> 4;        // reader role: h-subgroup 0..3
  const long hglob = (n0 >> 2) + (wn >> 2) + tq * 4;

  float4 bsum[4];
#pragma unroll
  for (int g = 0; g < 4; ++g) {
    const float4 a = *(const float4*)(bW + g * H_DIM + hglob);
    const float4 b = *(const float4*)(bU + g * H_DIM + hglob);
    bsum[g] = (float4){a.x + b.x, a.y + b.y, a.z + b.z, a.w + b.w};
  }

  float* wx = cex + wv * (16 * CEX_STRIDE);   // wave-private region
  const long BH = (long)B_DIM * H_DIM;

  for (int ig = 0; ig < 4; ++ig) {
    // stage this 16-row group's 64 cols into LDS [row16][col64]
#pragma unroll
    for (int j = 0; j < 4; ++j)
#pragma unroll
      for (int r = 0; r < 4; ++r)
        wx[(rquad + r) * CEX_STRIDE + j * 16 + col16] = acc[ig][j][r];

    // gather 4 gates per output as float4: col64 = h16*4 + g
    float4 g4[4];
#pragma unroll
    for (int t = 0; t < 4; ++t)
      g4[t] = *(const float4*)&wx[row16 * CEX_STRIDE + (tq * 4 + t) * 4];

    const long mrow = m0 + wm + ig * 16 + row16;
    const float4 cp4 = *(const float4*)(cprev_g + mrow * H_DIM + hglob);

    float hn[4], cn[4];
#pragma unroll
    for (int t = 0; t < 4; ++t) {
      const float gi = g4[t].x + getc(bsum[0], t);
      const float gf = g4[t].y + getc(bsum[1], t);
      const float go = g4[t].z + getc(bsum[2], t);
      const float gg = g4[t].w + getc(bsum[3], t);
      const float I = sigmoidf_(gi);
      const float F = sigmoidf_(gf);
      const float O = sigmoidf_(go);
      const float G = tanhf_(gg);
      const float cv = F * getc(cp4, t) + I * G;
      hn[t] = O * tanhf_(cv);
      cn[t] = cv;
    }
    const float4 hn4 = {hn[0], hn[1], hn[2], hn[3]};
    const float4 cn4 = {cn[0], cn[1], cn[2], cn[3]};
    const long ob = mrow * H_DIM + hglob;
    *(float4*)(out + ob)          = hn4;  // output 0: h_new
    *(float4*)(out + BH + ob)     = hn4;  // output 1: h_new (tuple dup)
    *(float4*)(out + 2 * BH + ob) = cn4;  // output 2: c_new
  }
}

extern "C" void kernel_launch(void* const* d_in, const int* in_sizes, int n_in,
                              void* d_out, int out_size, void* d_ws, size_t ws_size,
                              hipStream_t stream) {
  const float* x  = (const float*)d_in[0];
  const float* h  = (const float*)d_in[1];
  const float* c  = (const float*)d_in[2];
  const float* W  = (const float*)d_in[3];
  const float* bW = (const float*)d_in[4];
  const float* U  = (const float*)d_in[5];
  const float* bU = (const float*)d_in[6];
  float* out = (float*)d_out;

  bf16* Ac = (bf16*)d_ws;                               // 32 MB
  bf16* Bc = (bf16*)((char*)d_ws + (size_t)33554432);   // 16 MB

  cvt_pack_A<<<8192, 256, 0, stream>>>(x, h, Ac);
  cvt_pack_B<<<4096, 256, 0, stream>>>(W, U, Bc);
  // 64 m-tiles x 32 n-tiles, XCD-swizzled
  gemm_lstm<<<2048, 256, 0, stream>>>(Ac, Bc, c, bW, bU, out);
}

// Round 7
// 376.682 us; speedup vs baseline: 1.2418x; 1.0465x over previous
//
#include <hip/hip_runtime.h>
#include <hip/hip_bf16.h>

typedef __hip_bfloat16 bf16;
typedef __attribute__((ext_vector_type(8))) short short8;
typedef __attribute__((ext_vector_type(4))) float floatx4;

#define B_DIM 8192
#define H_DIM 1024
#define KSUM 2048      // fused K: 1024 (x·W) + 1024 (h·U)
#define BM 128
#define BN 128
#define BK 64
#define KITER 32       // 2048 / 64
#define CEX_STRIDE 68  // padded floats/row in C-exchange LDS

union BS { bf16 b; short s; };
__device__ __forceinline__ short cvt1(float f) {
  BS u; u.b = __float2bfloat16(f); return u.s;
}
__device__ __forceinline__ short8 cvt8(float4 lo, float4 hi) {
  short8 r;
  r[0] = cvt1(lo.x); r[1] = cvt1(lo.y); r[2] = cvt1(lo.z); r[3] = cvt1(lo.w);
  r[4] = cvt1(hi.x); r[5] = cvt1(hi.y); r[6] = cvt1(hi.z); r[7] = cvt1(hi.w);
  return r;
}

// async global->LDS, 16B/lane; lds dest = wave-uniform base + lane*16.
// NOTE: offset imm MUST be 0 — nonzero imm mis-addressed (round-6 failure).
__device__ __forceinline__ void async_ld16(const bf16* g, bf16* lds) {
  __builtin_amdgcn_global_load_lds(
      (const __attribute__((address_space(1))) unsigned int*)g,
      (__attribute__((address_space(3))) unsigned int*)lds,
      16, 0, 0);
}

// Fused converter.
// blk < 8192:  Ac[row][k] bf16: k<1024 -> x[row][k], else h[row][k-1024]
// blk >= 8192: Bc[r][k] bf16, gate-interleaved rows r = hh*4+g:
//              k<1024 -> W[g][hh][k], else U[g][hh][k-1024]
__global__ __launch_bounds__(256) void cvt_pack(
    const float* __restrict__ x, const float* __restrict__ h,
    const float* __restrict__ W, const float* __restrict__ U,
    bf16* __restrict__ Ac, bf16* __restrict__ Bc) {
  const int blk = blockIdx.x;
  if (blk < 8192) {
    const int idx = blk * 256 + threadIdx.x;   // 2M threads
    const long row = idx >> 8;
    const int k0 = (idx & 255) << 3;
    const float* src = (k0 < 1024) ? (x + row * 1024 + k0)
                                   : (h + row * 1024 + (k0 - 1024));
    const float4 lo = *(const float4*)src;
    const float4 hi = *(const float4*)(src + 4);
    *(short8*)(Ac + row * KSUM + k0) = cvt8(lo, hi);
  } else {
    const int idx = (blk - 8192) * 256 + threadIdx.x;   // 1M threads
    const long r = idx >> 8;
    const int k0 = (idx & 255) << 3;
    const int g = (int)(r & 3);
    const long hh = r >> 2;
    const long base = (long)g * (H_DIM * H_DIM) + hh * H_DIM;
    const float* src = (k0 < 1024) ? (W + base + k0) : (U + base + (k0 - 1024));
    const float4 lo = *(const float4*)src;
    const float4 hi = *(const float4*)(src + 4);
    *(short8*)(Bc + r * KSUM + k0) = cvt8(lo, hi);
  }
}

__device__ __forceinline__ float sigmoidf_(float v) {
  return 1.0f / (1.0f + __expf(-v));
}
__device__ __forceinline__ float tanhf_(float v) {
  return 1.0f - 2.0f / (__expf(2.0f * v) + 1.0f);  // safe at +/-inf
}
__device__ __forceinline__ float getc(const float4& v, int t) {
  return t == 0 ? v.x : t == 1 ? v.y : t == 2 ? v.z : v.w;
}

// GEMM M=8192,N=4096,K=2048 (bf16 MFMA) + fused LSTM epilogue.
// Explicit LDS double-buffer: prefetch tile kt+1 right after the barrier,
// compute tile kt from the other buffer -> the barrier's vmcnt drain overlaps
// a full compute phase. One barrier per K-iter.
// LDS tiles [row][chunk^(row&7)] XOR-swizzled (chunk = 16 B).
__global__ __launch_bounds__(256) void gemm_lstm(
    const bf16* __restrict__ Ac, const bf16* __restrict__ Bc,
    const float* __restrict__ cprev_g, const float* __restrict__ bW,
    const float* __restrict__ bU, float* __restrict__ out) {
  __shared__ __align__(16) char smem[65536];
  bf16* const sA0 = (bf16*)smem;              // buf0 A, 16 KB
  bf16* const sB0 = (bf16*)(smem + 16384);    // buf0 B
  bf16* const sA1 = (bf16*)(smem + 32768);    // buf1 A
  bf16* const sB1 = (bf16*)(smem + 49152);    // buf1 B
  float* const cex = (float*)smem;            // epilogue exchange

  const int tid  = threadIdx.x;
  const int lane = tid & 63;
  const int wv   = tid >> 6;

  // XCD-aware swizzle: xcd = blk&7; each XCD sweeps all 64 m-tiles against
  // one n-stripe (Bc stripe L2-resident), 4 stripes per XCD.
  const int blk  = blockIdx.x;
  const int xcd  = blk & 7;
  const int slot = blk >> 3;          // 0..255 per xcd
  const int mt   = slot & 63;
  const int nt   = (xcd << 2) | (slot >> 6);
  const long m0 = (long)mt * BM;
  const long n0 = (long)nt * BN;

  // staging: call q covers rows [q*32+wv*8, +8); lane -> (row lrow, chunk)
  const int lrow   = lane >> 3;           // row within 8-row group
  const int lchunk = lane & 7;            // dest chunk position
  const int schunk = lchunk ^ lrow;       // source chunk (XOR swizzle)
  const bf16* aSrc = Ac + (m0 + wv * 8 + lrow) * (long)KSUM + schunk * 8;
  const bf16* bSrc = Bc + (n0 + wv * 8 + lrow) * (long)KSUM + schunk * 8;
  bf16* const dA0 = sA0 + wv * 512;       // wave-uniform LDS bases
  bf16* const dB0 = sB0 + wv * 512;
  bf16* const dA1 = sA1 + wv * 512;
  bf16* const dB1 = sB1 + wv * 512;

  // compute phase: 2x2 wave grid, 4x4 MFMA frags each
  const int wm = ((wv >> 1) & 1) << 6;
  const int wn = (wv & 1) << 6;
  const int col16 = lane & 15;
  const int quad  = lane >> 4;
  const int x7    = col16 & 7;

  floatx4 acc[4][4];
#pragma unroll
  for (int i = 0; i < 4; ++i)
#pragma unroll
    for (int j = 0; j < 4; ++j) acc[i][j] = (floatx4){0.f, 0.f, 0.f, 0.f};

#define STAGE(kt, dA, dB)                                                 \
  {                                                                       \
    const long koff_ = (long)(kt) * BK;                                   \
    _Pragma("unroll")                                                     \
    for (int q = 0; q < 4; ++q) {                                         \
      async_ld16(aSrc + koff_ + (long)q * (32 * (long)KSUM), (dA) + q * 2048); \
      async_ld16(bSrc + koff_ + (long)q * (32 * (long)KSUM), (dB) + q * 2048); \
    }                                                                     \
  }

#define COMPUTE(sAp, sBp)                                                 \
  {                                                                       \
    _Pragma("unroll")                                                     \
    for (int s = 0; s < 2; ++s) {                                         \
      const int cp = ((((s << 2) + quad) ^ x7) << 3);                     \
      short8 af[4], bfr[4];                                               \
      _Pragma("unroll")                                                   \
      for (int i = 0; i < 4; ++i) {                                       \
        af[i]  = *(const short8*)&(sAp)[(wm + i * 16 + col16) * 64 + cp]; \
        bfr[i] = *(const short8*)&(sBp)[(wn + i * 16 + col16) * 64 + cp]; \
      }                                                                   \
      _Pragma("unroll")                                                   \
      for (int i = 0; i < 4; ++i)                                         \
        _Pragma("unroll")                                                 \
        for (int j = 0; j < 4; ++j)                                       \
          acc[i][j] = __builtin_amdgcn_mfma_f32_16x16x32_bf16(            \
              af[i], bfr[j], acc[i][j], 0, 0, 0);                         \
    }                                                                     \
  }

  STAGE(0, dA0, dB0);
#pragma unroll 1
  for (int kt = 0; kt < KITER; kt += 2) {
    __syncthreads();            // drains vmcnt: buf0's tile kt complete
    STAGE(kt + 1, dA1, dB1);    // prefetch next tile into buf1
    COMPUTE(sA0, sB0);          // compute tile kt from buf0
    __syncthreads();            // drains vmcnt: buf1's tile kt+1 complete
    if (kt + 2 < KITER) STAGE(kt + 2, dA0, dB0);
    COMPUTE(sA1, sB1);          // compute tile kt+1 from buf1
  }

  __syncthreads();  // repurpose LDS for C-exchange

  // ---- fused epilogue ----
  // C/D layout: col = lane&15, row = (lane>>4)*4 + reg
  const int rquad = (lane >> 4) << 2;
  const int row16 = lane & 15;        // reader role: local output row
  const int tq    = lane >> 4;        // reader role: h-subgroup 0..3
  const long hglob = (n0 >> 2) + (wn >> 2) + tq * 4;

  float4 bsum[4];
#pragma unroll
  for (int g = 0; g < 4; ++g) {
    const float4 a = *(const float4*)(bW + g * H_DIM + hglob);
    const float4 b = *(const float4*)(bU + g * H_DIM + hglob);
    bsum[g] = (float4){a.x + b.x, a.y + b.y, a.z + b.z, a.w + b.w};
  }

  float* wx = cex + wv * (16 * CEX_STRIDE);   // wave-private region
  const long BH = (long)B_DIM * H_DIM;

  for (int ig = 0; ig < 4; ++ig) {
    // stage this 16-row group's 64 cols into LDS [row16][col64]
#pragma unroll
    for (int j = 0; j < 4; ++j)
#pragma unroll
      for (int r = 0; r < 4; ++r)
        wx[(rquad + r) * CEX_STRIDE + j * 16 + col16] = acc[ig][j][r];

    // gather 4 gates per output as float4: col64 = h16*4 + g
    float4 g4[4];
#pragma unroll
    for (int t = 0; t < 4; ++t)
      g4[t] = *(const float4*)&wx[row16 * CEX_STRIDE + (tq * 4 + t) * 4];

    const long mrow = m0 + wm + ig * 16 + row16;
    const float4 cp4 = *(const float4*)(cprev_g + mrow * H_DIM + hglob);

    float hn[4], cn[4];
#pragma unroll
    for (int t = 0; t < 4; ++t) {
      const float gi = g4[t].x + getc(bsum[0], t);
      const float gf = g4[t].y + getc(bsum[1], t);
      const float go = g4[t].z + getc(bsum[2], t);
      const float gg = g4[t].w + getc(bsum[3], t);
      const float I = sigmoidf_(gi);
      const float F = sigmoidf_(gf);
      const float O = sigmoidf_(go);
      const float G = tanhf_(gg);
      const float cv = F * getc(cp4, t) + I * G;
      hn[t] = O * tanhf_(cv);
      cn[t] = cv;
    }
    const float4 hn4 = {hn[0], hn[1], hn[2], hn[3]};
    const float4 cn4 = {cn[0], cn[1], cn[2], cn[3]};
    const long ob = mrow * H_DIM + hglob;
    *(float4*)(out + ob)          = hn4;  // output 0: h_new
    *(float4*)(out + BH + ob)     = hn4;  // output 1: h_new (tuple dup)
    *(float4*)(out + 2 * BH + ob) = cn4;  // output 2: c_new
  }
}

extern "C" void kernel_launch(void* const* d_in, const int* in_sizes, int n_in,
                              void* d_out, int out_size, void* d_ws, size_t ws_size,
                              hipStream_t stream) {
  const float* x  = (const float*)d_in[0];
  const float* h  = (const float*)d_in[1];
  const float* c  = (const float*)d_in[2];
  const float* W  = (const float*)d_in[3];
  const float* bW = (const float*)d_in[4];
  const float* U  = (const float*)d_in[5];
  const float* bU = (const float*)d_in[6];
  float* out = (float*)d_out;

  bf16* Ac = (bf16*)d_ws;                               // 32 MB
  bf16* Bc = (bf16*)((char*)d_ws + (size_t)33554432);   // 16 MB

  cvt_pack<<<12288, 256, 0, stream>>>(x, h, W, U, Ac, Bc);
  // 64 m-tiles x 32 n-tiles, XCD-swizzled
  gemm_lstm<<<2048, 256, 0, stream>>>(Ac, Bc, c, bW, bU, out);
}